// Round 9
// baseline (139.289 us; speedup 1.0000x reference)
//
#include <hip/hip_runtime.h>
#include <hip/hip_fp16.h>

#define Bn   4
#define CINc 64
#define COUTc 64
#define Hn   128
#define Wn   128
#define HW   (Hn * Wn)
#define KKc  9
#define NOFF 18

typedef short bf16x8 __attribute__((ext_vector_type(8)));
typedef float f32x4  __attribute__((ext_vector_type(4)));

__device__ inline unsigned short f2bf(float f) {   // RNE fp32 -> bf16
    unsigned int u = __float_as_uint(f);
    return (unsigned short)((u + 0x7fffu + ((u >> 16) & 1u)) >> 16);
}

// ---------------------------------------------------------------------------
// prep_all: blocks 0..1023 transpose x -> channel-last bf16 xt;
// blocks 1024..1239 build lane-order swizzled weight tables.
//   wkb_sw[seg=(k*2+kc)*4+ot][lane][j] = w_def[ot*16+l15][kc*32+quad*8+j][k]
//   wob_sw[seg=(t*2+kc)*2+mt][lane][j] = w_off[mt*16+l15][kc*32+quad*8+j][t]
// ---------------------------------------------------------------------------
__global__ __launch_bounds__(256) void prep_all(
        const float* __restrict__ x, unsigned short* __restrict__ xt,
        const float* __restrict__ w_off, const float* __restrict__ w_def,
        unsigned short* __restrict__ wkb_sw, unsigned short* __restrict__ wob_sw) {
    int gb = blockIdx.x;
    int t  = threadIdx.x;
    if (gb < 1024) {
        __shared__ float s[64][65];
        int half = gb & 1;
        int h    = (gb >> 1) & 127;
        int b    = gb >> 8;
        int w0   = half * 64;
        int w = t & 63, cg = t >> 6;

        const float* xb = x + (size_t)b * CINc * HW + (size_t)h * Wn + w0 + w;
        #pragma unroll
        for (int i = 0; i < 16; ++i) {
            int c = cg * 16 + i;
            s[c][w] = xb[(size_t)c * HW];
        }
        __syncthreads();

        int cpair = t & 31, pxg = t >> 5;
        unsigned* xtp = (unsigned*)xt;
        #pragma unroll
        for (int i = 0; i < 8; ++i) {
            int px = pxg * 8 + i;
            float v0 = s[cpair * 2][px], v1 = s[cpair * 2 + 1][px];
            unsigned d = (unsigned)f2bf(v0) | ((unsigned)f2bf(v1) << 16);
            xtp[(((size_t)(b * Hn + h) * Wn) + w0 + px) * 32 + cpair] = d;
        }
        return;
    }
    int idx = (gb - 1024) * 256 + t;
    if (idx < 36864) {
        int j = idx & 7, l = (idx >> 3) & 63, s = idx >> 9;
        int k = s >> 3, kc = (s >> 2) & 1, ot = s & 3;
        int l15 = l & 15, quad = l >> 4;
        int o = ot * 16 + l15, c = kc * 32 + quad * 8 + j;
        wkb_sw[idx] = f2bf(w_def[((size_t)o * 64 + c) * 9 + k]);
    }
    int i2 = idx - 36864;
    if (i2 >= 0 && i2 < 18432) {
        int j = i2 & 7, l = (i2 >> 3) & 63, s = i2 >> 9;
        int tt = s >> 2, kc = (s >> 1) & 1, mt = s & 1;
        int l15 = l & 15, quad = l >> 4;
        int m = mt * 16 + l15, c = kc * 32 + quad * 8 + j;
        unsigned short v = 0;
        if (m < NOFF) v = f2bf(w_off[((size_t)m * 64 + c) * 9 + tt]);
        wob_sw[i2] = v;
    }
}

// ---------------------------------------------------------------------------
// Fused deformable conv v8. Block = (b,h,64-px half), 1024 blocks, 256 thr.
// Key identity: the lane producing off[oc=quad*4+r][px=wave*16+l15] in the
// offset phase is the SAME lane that owns pixel px in the main loop, and
// taps k=2q,2q+1 (+k=8 on q0) consume exactly oc=4q..4q+3 (16,17) = its own
// accumulators -> phase-1 runs fully in-register, no off hand-off at all.
// s_w LDS buffer is time-shared: wob (offset A-frags) -> overwritten by wkb
// (main A-frags, prefetched to registers during phase-1). 3 barriers.
// ---------------------------------------------------------------------------
__global__ __launch_bounds__(256, 2) void fused_deform_v8(
        const unsigned short* __restrict__ xt,
        const unsigned short* __restrict__ wob_sw,
        const unsigned short* __restrict__ wkb_sw,
        const float* __restrict__ b_off, float* __restrict__ out) {
    __shared__ bf16x8   s_w[72 * 64];       // 73728 B (wob first, then wkb)
    __shared__ unsigned s_ad[KKc][64];      // yc0 | yc1<<8 | xc<<16
    __shared__ __half2  s_wh[KKc][64][2];   // folded corner weights

    int gid  = blockIdx.x;                  // 1024
    int xcd  = gid & 7;
    int j    = gid >> 3;
    int half = j & 1;
    int hh   = (j >> 1) & 15;
    int b    = (j >> 5) & 3;
    int h    = xcd * 16 + hh;
    int w0   = half * 64;
    int tid  = threadIdx.x;
    int lane = tid & 63;
    int wave = __builtin_amdgcn_readfirstlane(tid >> 6);
    int l15  = lane & 15;
    int quad = lane >> 4;
    int px_blk = wave * 16 + l15;           // this lane's block-pixel
    int p    = w0 + px_blk;                 // global pixel col

    // ---- stage wob -> s_w[0..36*64) ----
    #pragma unroll
    for (int i = 0; i < 9; ++i) {
        int e = tid + i * 256;
        ((uint4*)s_w)[e] = ((const uint4*)wob_sw)[e];
    }

    // ---- prefetch the 18 offset-tap fragments ----
    uint4 L[9][2];
    unsigned msk[9];
    const unsigned short* xtb = xt + (size_t)b * HW * 64;
    #pragma unroll
    for (int t9 = 0; t9 < 9; ++t9) {
        int ty = t9 / 3, tx = t9 % 3;
        int y  = h - 1 + ty;
        int xg = p - 1 + tx;
        bool v = (y >= 0) && (y < Hn) && (xg >= 0) && (xg < Wn);
        msk[t9] = v ? 0xFFFFFFFFu : 0u;
        int yc = min(max(y, 0), Hn - 1);
        int xc = min(max(xg, 0), Wn - 1);
        size_t base = ((size_t)yc * Wn + xc) * 64;
        L[t9][0] = *(const uint4*)(xtb + base + quad * 8);
        L[t9][1] = *(const uint4*)(xtb + base + 32 + quad * 8);
    }
    __syncthreads();                        // bar0: wob visible

    // ---- offset conv phase: 36 MFMA ----
    f32x4 oa0 = (f32x4){0.f, 0.f, 0.f, 0.f};
    f32x4 oa1 = (f32x4){0.f, 0.f, 0.f, 0.f};
    #pragma unroll
    for (int t9 = 0; t9 < 9; ++t9) {
        unsigned m = msk[t9];
        #pragma unroll
        for (int kc = 0; kc < 2; ++kc) {
            union { bf16x8 v; uint4 u; } bf;
            bf.u = L[t9][kc];
            bf.u.x &= m; bf.u.y &= m; bf.u.z &= m; bf.u.w &= m;
            bf16x8 a0 = s_w[((t9 * 2 + kc) * 2 + 0) * 64 + lane];
            bf16x8 a1 = s_w[((t9 * 2 + kc) * 2 + 1) * 64 + lane];
            oa0 = __builtin_amdgcn_mfma_f32_16x16x32_bf16(a0, bf.v, oa0, 0, 0, 0);
            oa1 = __builtin_amdgcn_mfma_f32_16x16x32_bf16(a1, bf.v, oa1, 0, 0, 0);
        }
    }

    // ---- prefetch wkb -> registers (cover: phase-1 VALU below) ----
    uint4 W18[18];
    #pragma unroll
    for (int i = 0; i < 18; ++i)
        W18[i] = ((const uint4*)wkb_sw)[tid + i * 256];

    // ---- phase-1, fully in-register (lane owns taps 2q,2q+1 [,8]) ----
    auto phase1 = [&](int k, float dy, float dx) {
        float py  = (float)(h - 1 + k / 3) + dy;
        float pxf = (float)(p - 1 + k % 3) + dx;
        float y0f = floorf(py), x0f = floorf(pxf);
        float fy = py - y0f, fx = pxf - x0f;
        int y0 = (int)y0f, x0 = (int)x0f;
        bool vy0 = (y0 >= 0) & (y0 < Hn);
        bool vy1 = (y0 + 1 >= 0) & (y0 + 1 < Hn);
        bool vx0 = (x0 >= 0) & (x0 < Wn);
        bool vx1 = (x0 + 1 >= 0) & (x0 + 1 < Wn);
        float wy0 = vy0 ? 1.f - fy : 0.f;
        float wy1 = vy1 ? fy : 0.f;
        float wx0 = vx0 ? 1.f - fx : 0.f;
        float wx1 = vx1 ? fx : 0.f;
        int xc = min(max(x0, 0), Wn - 2);               // pair base
        bool sel0 = (min(max(x0, 0), Wn - 1) != xc);
        bool sel1 = ((min(max(x0 + 1, 0), Wn - 1) - xc) == 1);
        float Wa = (sel0 ? 0.f : wx0) + (sel1 ? 0.f : wx1);
        float Wb = (sel0 ? wx0 : 0.f) + (sel1 ? wx1 : 0.f);
        int yc0 = min(max(y0, 0), Hn - 1), yc1 = min(max(y0 + 1, 0), Hn - 1);
        s_ad[k][px_blk] = (unsigned)yc0 | ((unsigned)yc1 << 8) | ((unsigned)xc << 16);
        s_wh[k][px_blk][0] = __floats2half2_rn(wy0 * Wa, wy0 * Wb);
        s_wh[k][px_blk][1] = __floats2half2_rn(wy1 * Wa, wy1 * Wb);
    };
    int kb = quad * 2;
    phase1(kb,     oa0[0] + b_off[4 * quad],     oa0[1] + b_off[4 * quad + 1]);
    phase1(kb + 1, oa0[2] + b_off[4 * quad + 2], oa0[3] + b_off[4 * quad + 3]);
    if (quad == 0)
        phase1(8, oa1[0] + b_off[16], oa1[1] + b_off[17]);
    __syncthreads();                        // bar1: s_ad/s_wh done, wob reads done

    // ---- overwrite s_w with wkb ----
    #pragma unroll
    for (int i = 0; i < 18; ++i)
        ((uint4*)s_w)[tid + i * 256] = W18[i];
    __syncthreads();                        // bar2: wkb visible

    // ---- preload per-lane addr/weights for all k ----
    unsigned at[KKc], ab[KKc];
    float Wf[KKc][4];
    #pragma unroll
    for (int k = 0; k < KKc; ++k) {
        unsigned ad = s_ad[k][px_blk];
        int xc = (int)(ad >> 16);
        at[k] = (unsigned)(((ad & 255u) * Wn + xc) * 64);
        ab[k] = (unsigned)((((ad >> 8) & 255u) * Wn + xc) * 64);
        __half2 w01 = s_wh[k][px_blk][0], w23 = s_wh[k][px_blk][1];
        Wf[k][0] = __low2float(w01); Wf[k][1] = __high2float(w01);
        Wf[k][2] = __low2float(w23); Wf[k][3] = __high2float(w23);
    }

    f32x4 acc[4];
    #pragma unroll
    for (int ot = 0; ot < 4; ++ot) acc[ot] = (f32x4){0.f, 0.f, 0.f, 0.f};

    // ---- software-pipelined barrier-free main loop ----
    uint4 R[2][8];
    int co0 = quad * 8, co1 = 32 + quad * 8;

    #define FETCH(kk, st)                                            \
        do {                                                         \
            R[st][0] = *(const uint4*)(xtb + at[kk] + co0);          \
            R[st][1] = *(const uint4*)(xtb + at[kk] + 64 + co0);     \
            R[st][2] = *(const uint4*)(xtb + ab[kk] + co0);          \
            R[st][3] = *(const uint4*)(xtb + ab[kk] + 64 + co0);     \
            R[st][4] = *(const uint4*)(xtb + at[kk] + co1);          \
            R[st][5] = *(const uint4*)(xtb + at[kk] + 64 + co1);     \
            R[st][6] = *(const uint4*)(xtb + ab[kk] + co1);          \
            R[st][7] = *(const uint4*)(xtb + ab[kk] + 64 + co1);     \
        } while (0)

    FETCH(0, 0);
    #pragma unroll
    for (int k = 0; k < KKc; ++k) {
        if (k < KKc - 1) FETCH(k + 1, (k + 1) & 1);
        const uint4* C = R[k & 1];
        float W0 = Wf[k][0], W1 = Wf[k][1], W2 = Wf[k][2], W3 = Wf[k][3];
        #pragma unroll
        for (int kc = 0; kc < 2; ++kc) {
            const unsigned* t0 = (const unsigned*)&C[kc * 4 + 0];
            const unsigned* t1 = (const unsigned*)&C[kc * 4 + 1];
            const unsigned* b0 = (const unsigned*)&C[kc * 4 + 2];
            const unsigned* b1 = (const unsigned*)&C[kc * 4 + 3];
            union { bf16x8 v; unsigned u[4]; } bf;
            #pragma unroll
            for (int jd = 0; jd < 4; ++jd) {
                float t0l = __uint_as_float(t0[jd] << 16);
                float t0h = __uint_as_float(t0[jd] & 0xFFFF0000u);
                float t1l = __uint_as_float(t1[jd] << 16);
                float t1h = __uint_as_float(t1[jd] & 0xFFFF0000u);
                float b0l = __uint_as_float(b0[jd] << 16);
                float b0h = __uint_as_float(b0[jd] & 0xFFFF0000u);
                float b1l = __uint_as_float(b1[jd] << 16);
                float b1h = __uint_as_float(b1[jd] & 0xFFFF0000u);
                float vl = W0 * t0l + W1 * t1l + W2 * b0l + W3 * b1l;
                float vh = W0 * t0h + W1 * t1h + W2 * b0h + W3 * b1h;
                bf.u[jd] = (unsigned)f2bf(vl) | ((unsigned)f2bf(vh) << 16);
            }
            #pragma unroll
            for (int ot = 0; ot < 4; ++ot) {
                bf16x8 af = s_w[((k * 2 + kc) * 4 + ot) * 64 + lane];
                acc[ot] = __builtin_amdgcn_mfma_f32_16x16x32_bf16(af, bf.v, acc[ot], 0, 0, 0);
            }
        }
    }
    #undef FETCH

    #pragma unroll
    for (int ot = 0; ot < 4; ++ot)
        #pragma unroll
        for (int r = 0; r < 4; ++r) {
            int o = ot * 16 + quad * 4 + r;
            out[(((size_t)b * COUTc + o) * Hn + h) * Wn + p] = acc[ot][r];
        }
}

// ---------------------------------------------------------------------------
extern "C" void kernel_launch(void* const* d_in, const int* in_sizes, int n_in,
                              void* d_out, int out_size, void* d_ws, size_t ws_size,
                              hipStream_t stream) {
    const float* x     = (const float*)d_in[0];
    const float* w_off = (const float*)d_in[1];
    const float* b_off = (const float*)d_in[2];
    const float* w_def = (const float*)d_in[3];
    float* out = (float*)d_out;

    char* ws = (char*)d_ws;
    unsigned short* xt = (unsigned short*)ws;                 // 8.39 MB
    ws += (size_t)Bn * HW * CINc * sizeof(unsigned short);
    unsigned short* wkb_sw = (unsigned short*)ws;             // 73728 B
    ws += 36864 * sizeof(unsigned short);
    unsigned short* wob_sw = (unsigned short*)ws;             // 36864 B

    prep_all<<<1024 + 216, 256, 0, stream>>>(x, xt, w_off, w_def, wkb_sw, wob_sw);
    fused_deform_v8<<<Bn * Hn * (Wn / 64), 256, 0, stream>>>(xt, wob_sw, wkb_sw, b_off, out);
}

// Round 10
// 118.335 us; speedup vs baseline: 1.1771x; 1.1771x over previous
//
#include <hip/hip_runtime.h>
#include <hip/hip_fp16.h>

#define Bn   4
#define CINc 64
#define COUTc 64
#define Hn   128
#define Wn   128
#define HW   (Hn * Wn)
#define KKc  9
#define NOFF 18

typedef short bf16x8 __attribute__((ext_vector_type(8)));
typedef float f32x4  __attribute__((ext_vector_type(4)));

__device__ inline unsigned short f2bf(float f) {   // RNE fp32 -> bf16
    unsigned int u = __float_as_uint(f);
    return (unsigned short)((u + 0x7fffu + ((u >> 16) & 1u)) >> 16);
}

// 16B global -> LDS DMA (no VGPR round-trip). lds base must be wave-uniform;
// HW writes each lane's 16B at ldsbase + lane*16.
__device__ inline void dma16(const void* g, void* l) {
#if __has_builtin(__builtin_amdgcn_global_load_lds)
    __builtin_amdgcn_global_load_lds(
        (__attribute__((address_space(1))) void*)(g),
        (__attribute__((address_space(3))) void*)(l), 16, 0, 0);
#else
    *(uint4*)l = *(const uint4*)g;   // fallback (never taken on gfx950)
#endif
}

// ---------------------------------------------------------------------------
// prep_all: blocks 0..1023 transpose x -> channel-last bf16 xt;
// blocks 1024..1239 build lane-order swizzled weight tables.
//   wkb_sw[seg=(k*2+kc)*4+ot][lane][j] = w_def[ot*16+l15][kc*32+quad*8+j][k]
//   wob_sw[seg=(t*2+kc)*2+mt][lane][j] = w_off[mt*16+l15][kc*32+quad*8+j][t]
// ---------------------------------------------------------------------------
__global__ __launch_bounds__(256) void prep_all(
        const float* __restrict__ x, unsigned short* __restrict__ xt,
        const float* __restrict__ w_off, const float* __restrict__ w_def,
        unsigned short* __restrict__ wkb_sw, unsigned short* __restrict__ wob_sw) {
    int gb = blockIdx.x;
    int t  = threadIdx.x;
    if (gb < 1024) {
        __shared__ float s[64][65];
        int half = gb & 1;
        int h    = (gb >> 1) & 127;
        int b    = gb >> 8;
        int w0   = half * 64;
        int w = t & 63, cg = t >> 6;

        const float* xb = x + (size_t)b * CINc * HW + (size_t)h * Wn + w0 + w;
        #pragma unroll
        for (int i = 0; i < 16; ++i) {
            int c = cg * 16 + i;
            s[c][w] = xb[(size_t)c * HW];
        }
        __syncthreads();

        int cpair = t & 31, pxg = t >> 5;
        unsigned* xtp = (unsigned*)xt;
        #pragma unroll
        for (int i = 0; i < 8; ++i) {
            int px = pxg * 8 + i;
            float v0 = s[cpair * 2][px], v1 = s[cpair * 2 + 1][px];
            unsigned d = (unsigned)f2bf(v0) | ((unsigned)f2bf(v1) << 16);
            xtp[(((size_t)(b * Hn + h) * Wn) + w0 + px) * 32 + cpair] = d;
        }
        return;
    }
    int idx = (gb - 1024) * 256 + t;
    if (idx < 36864) {
        int j = idx & 7, l = (idx >> 3) & 63, s = idx >> 9;
        int k = s >> 3, kc = (s >> 2) & 1, ot = s & 3;
        int l15 = l & 15, quad = l >> 4;
        int o = ot * 16 + l15, c = kc * 32 + quad * 8 + j;
        wkb_sw[idx] = f2bf(w_def[((size_t)o * 64 + c) * 9 + k]);
    }
    int i2 = idx - 36864;
    if (i2 >= 0 && i2 < 18432) {
        int j = i2 & 7, l = (i2 >> 3) & 63, s = i2 >> 9;
        int tt = s >> 2, kc = (s >> 1) & 1, mt = s & 1;
        int l15 = l & 15, quad = l >> 4;
        int m = mt * 16 + l15, c = kc * 32 + quad * 8 + j;
        unsigned short v = 0;
        if (m < NOFF) v = f2bf(w_off[((size_t)m * 64 + c) * 9 + tt]);
        wob_sw[i2] = v;
    }
}

// ---------------------------------------------------------------------------
// Fused deformable conv v9 = v8 with DMA weight staging (fixes the 74 MB
// register-spill round-trip that sank v8). Block = (b,h,64-px half).
// Phases: [wob DMA + 18-tap prefetch] bar0 [offset MFMA, in-register phase-1]
// bar1 [wkb DMA] bar2 [barrier-free pipelined gather+blend+MFMA] [store].
// ---------------------------------------------------------------------------
__global__ __launch_bounds__(256, 2) void fused_deform_v9(
        const unsigned short* __restrict__ xt,
        const unsigned short* __restrict__ wob_sw,
        const unsigned short* __restrict__ wkb_sw,
        const float* __restrict__ b_off, float* __restrict__ out) {
    __shared__ bf16x8   s_w[72 * 64];       // 73728 B (wob first, then wkb)
    __shared__ unsigned s_ad[KKc][64];      // yc0 | yc1<<8 | xc<<16
    __shared__ __half2  s_wh[KKc][64][2];   // folded corner weights

    int gid  = blockIdx.x;                  // 1024
    int xcd  = gid & 7;
    int j    = gid >> 3;
    int half = j & 1;
    int hh   = (j >> 1) & 15;
    int b    = (j >> 5) & 3;
    int h    = xcd * 16 + hh;
    int w0   = half * 64;
    int tid  = threadIdx.x;
    int lane = tid & 63;
    int wave = __builtin_amdgcn_readfirstlane(tid >> 6);
    int l15  = lane & 15;
    int quad = lane >> 4;
    int px_blk = wave * 16 + l15;           // this lane's block-pixel
    int p    = w0 + px_blk;                 // global pixel col

    // ---- stage wob -> s_w[0..36*64) via DMA (zero VGPR) ----
    {
        int wbase = wave * 64;              // scalar
        #pragma unroll
        for (int i = 0; i < 9; ++i) {
            int ebase = i * 256 + wbase;    // wave-uniform element base
            dma16((const uint4*)wob_sw + ebase + lane,
                  (char*)s_w + (size_t)ebase * 16);
        }
    }

    // ---- prefetch the 18 offset-tap fragments ----
    uint4 L[9][2];
    unsigned msk[9];
    const unsigned short* xtb = xt + (size_t)b * HW * 64;
    #pragma unroll
    for (int t9 = 0; t9 < 9; ++t9) {
        int ty = t9 / 3, tx = t9 % 3;
        int y  = h - 1 + ty;
        int xg = p - 1 + tx;
        bool v = (y >= 0) && (y < Hn) && (xg >= 0) && (xg < Wn);
        msk[t9] = v ? 0xFFFFFFFFu : 0u;
        int yc = min(max(y, 0), Hn - 1);
        int xc = min(max(xg, 0), Wn - 1);
        size_t base = ((size_t)yc * Wn + xc) * 64;
        L[t9][0] = *(const uint4*)(xtb + base + quad * 8);
        L[t9][1] = *(const uint4*)(xtb + base + 32 + quad * 8);
    }
    __syncthreads();                        // bar0: wob DMA + prefetch drained

    // ---- offset conv phase: 36 MFMA ----
    f32x4 oa0 = (f32x4){0.f, 0.f, 0.f, 0.f};
    f32x4 oa1 = (f32x4){0.f, 0.f, 0.f, 0.f};
    #pragma unroll
    for (int t9 = 0; t9 < 9; ++t9) {
        unsigned m = msk[t9];
        #pragma unroll
        for (int kc = 0; kc < 2; ++kc) {
            union { bf16x8 v; uint4 u; } bf;
            bf.u = L[t9][kc];
            bf.u.x &= m; bf.u.y &= m; bf.u.z &= m; bf.u.w &= m;
            bf16x8 a0 = s_w[((t9 * 2 + kc) * 2 + 0) * 64 + lane];
            bf16x8 a1 = s_w[((t9 * 2 + kc) * 2 + 1) * 64 + lane];
            oa0 = __builtin_amdgcn_mfma_f32_16x16x32_bf16(a0, bf.v, oa0, 0, 0, 0);
            oa1 = __builtin_amdgcn_mfma_f32_16x16x32_bf16(a1, bf.v, oa1, 0, 0, 0);
        }
    }

    // ---- phase-1, fully in-register (lane owns taps 2q,2q+1 [,8]) ----
    auto phase1 = [&](int k, float dy, float dx) {
        float py  = (float)(h - 1 + k / 3) + dy;
        float pxf = (float)(p - 1 + k % 3) + dx;
        float y0f = floorf(py), x0f = floorf(pxf);
        float fy = py - y0f, fx = pxf - x0f;
        int y0 = (int)y0f, x0 = (int)x0f;
        bool vy0 = (y0 >= 0) & (y0 < Hn);
        bool vy1 = (y0 + 1 >= 0) & (y0 + 1 < Hn);
        bool vx0 = (x0 >= 0) & (x0 < Wn);
        bool vx1 = (x0 + 1 >= 0) & (x0 + 1 < Wn);
        float wy0 = vy0 ? 1.f - fy : 0.f;
        float wy1 = vy1 ? fy : 0.f;
        float wx0 = vx0 ? 1.f - fx : 0.f;
        float wx1 = vx1 ? fx : 0.f;
        int xc = min(max(x0, 0), Wn - 2);               // pair base
        bool sel0 = (min(max(x0, 0), Wn - 1) != xc);
        bool sel1 = ((min(max(x0 + 1, 0), Wn - 1) - xc) == 1);
        float Wa = (sel0 ? 0.f : wx0) + (sel1 ? 0.f : wx1);
        float Wb = (sel0 ? wx0 : 0.f) + (sel1 ? wx1 : 0.f);
        int yc0 = min(max(y0, 0), Hn - 1), yc1 = min(max(y0 + 1, 0), Hn - 1);
        s_ad[k][px_blk] = (unsigned)yc0 | ((unsigned)yc1 << 8) | ((unsigned)xc << 16);
        s_wh[k][px_blk][0] = __floats2half2_rn(wy0 * Wa, wy0 * Wb);
        s_wh[k][px_blk][1] = __floats2half2_rn(wy1 * Wa, wy1 * Wb);
    };
    int kb = quad * 2;
    phase1(kb,     oa0[0] + b_off[4 * quad],     oa0[1] + b_off[4 * quad + 1]);
    phase1(kb + 1, oa0[2] + b_off[4 * quad + 2], oa0[3] + b_off[4 * quad + 3]);
    if (quad == 0)
        phase1(8, oa1[0] + b_off[16], oa1[1] + b_off[17]);
    __syncthreads();                        // bar1: wob reads + phase-1 done

    // ---- overwrite s_w with wkb via DMA (the v8 spill, eliminated) ----
    {
        int wbase = wave * 64;
        #pragma unroll
        for (int i = 0; i < 18; ++i) {
            int ebase = i * 256 + wbase;
            dma16((const uint4*)wkb_sw + ebase + lane,
                  (char*)s_w + (size_t)ebase * 16);
        }
    }
    __syncthreads();                        // bar2: wkb visible

    // ---- preload per-lane addr/weights for all k ----
    unsigned at[KKc], ab[KKc];
    float Wf[KKc][4];
    #pragma unroll
    for (int k = 0; k < KKc; ++k) {
        unsigned ad = s_ad[k][px_blk];
        int xc = (int)(ad >> 16);
        at[k] = (unsigned)(((ad & 255u) * Wn + xc) * 64);
        ab[k] = (unsigned)((((ad >> 8) & 255u) * Wn + xc) * 64);
        __half2 w01 = s_wh[k][px_blk][0], w23 = s_wh[k][px_blk][1];
        Wf[k][0] = __low2float(w01); Wf[k][1] = __high2float(w01);
        Wf[k][2] = __low2float(w23); Wf[k][3] = __high2float(w23);
    }

    f32x4 acc[4];
    #pragma unroll
    for (int ot = 0; ot < 4; ++ot) acc[ot] = (f32x4){0.f, 0.f, 0.f, 0.f};

    // ---- software-pipelined barrier-free main loop ----
    uint4 R[2][8];
    int co0 = quad * 8, co1 = 32 + quad * 8;

    #define FETCH(kk, st)                                            \
        do {                                                         \
            R[st][0] = *(const uint4*)(xtb + at[kk] + co0);          \
            R[st][1] = *(const uint4*)(xtb + at[kk] + 64 + co0);     \
            R[st][2] = *(const uint4*)(xtb + ab[kk] + co0);          \
            R[st][3] = *(const uint4*)(xtb + ab[kk] + 64 + co0);     \
            R[st][4] = *(const uint4*)(xtb + at[kk] + co1);          \
            R[st][5] = *(const uint4*)(xtb + at[kk] + 64 + co1);     \
            R[st][6] = *(const uint4*)(xtb + ab[kk] + co1);          \
            R[st][7] = *(const uint4*)(xtb + ab[kk] + 64 + co1);     \
        } while (0)

    FETCH(0, 0);
    #pragma unroll
    for (int k = 0; k < KKc; ++k) {
        if (k < KKc - 1) FETCH(k + 1, (k + 1) & 1);
        const uint4* C = R[k & 1];
        float W0 = Wf[k][0], W1 = Wf[k][1], W2 = Wf[k][2], W3 = Wf[k][3];
        #pragma unroll
        for (int kc = 0; kc < 2; ++kc) {
            const unsigned* t0 = (const unsigned*)&C[kc * 4 + 0];
            const unsigned* t1 = (const unsigned*)&C[kc * 4 + 1];
            const unsigned* b0 = (const unsigned*)&C[kc * 4 + 2];
            const unsigned* b1 = (const unsigned*)&C[kc * 4 + 3];
            union { bf16x8 v; unsigned u[4]; } bf;
            #pragma unroll
            for (int jd = 0; jd < 4; ++jd) {
                float t0l = __uint_as_float(t0[jd] << 16);
                float t0h = __uint_as_float(t0[jd] & 0xFFFF0000u);
                float t1l = __uint_as_float(t1[jd] << 16);
                float t1h = __uint_as_float(t1[jd] & 0xFFFF0000u);
                float b0l = __uint_as_float(b0[jd] << 16);
                float b0h = __uint_as_float(b0[jd] & 0xFFFF0000u);
                float b1l = __uint_as_float(b1[jd] << 16);
                float b1h = __uint_as_float(b1[jd] & 0xFFFF0000u);
                float vl = W0 * t0l + W1 * t1l + W2 * b0l + W3 * b1l;
                float vh = W0 * t0h + W1 * t1h + W2 * b0h + W3 * b1h;
                bf.u[jd] = (unsigned)f2bf(vl) | ((unsigned)f2bf(vh) << 16);
            }
            #pragma unroll
            for (int ot = 0; ot < 4; ++ot) {
                bf16x8 af = s_w[((k * 2 + kc) * 4 + ot) * 64 + lane];
                acc[ot] = __builtin_amdgcn_mfma_f32_16x16x32_bf16(af, bf.v, acc[ot], 0, 0, 0);
            }
        }
    }
    #undef FETCH

    #pragma unroll
    for (int ot = 0; ot < 4; ++ot)
        #pragma unroll
        for (int r = 0; r < 4; ++r) {
            int o = ot * 16 + quad * 4 + r;
            out[(((size_t)b * COUTc + o) * Hn + h) * Wn + p] = acc[ot][r];
        }
}

// ---------------------------------------------------------------------------
extern "C" void kernel_launch(void* const* d_in, const int* in_sizes, int n_in,
                              void* d_out, int out_size, void* d_ws, size_t ws_size,
                              hipStream_t stream) {
    const float* x     = (const float*)d_in[0];
    const float* w_off = (const float*)d_in[1];
    const float* b_off = (const float*)d_in[2];
    const float* w_def = (const float*)d_in[3];
    float* out = (float*)d_out;

    char* ws = (char*)d_ws;
    unsigned short* xt = (unsigned short*)ws;                 // 8.39 MB
    ws += (size_t)Bn * HW * CINc * sizeof(unsigned short);
    unsigned short* wkb_sw = (unsigned short*)ws;             // 73728 B
    ws += 36864 * sizeof(unsigned short);
    unsigned short* wob_sw = (unsigned short*)ws;             // 36864 B

    prep_all<<<1024 + 216, 256, 0, stream>>>(x, xt, w_off, w_def, wkb_sw, wob_sw);
    fused_deform_v9<<<Bn * Hn * (Wn / 64), 256, 0, stream>>>(xt, wob_sw, wkb_sw, b_off, out);
}

// Round 11
// 115.395 us; speedup vs baseline: 1.2071x; 1.0255x over previous
//
#include <hip/hip_runtime.h>
#include <hip/hip_fp16.h>

#define Bn   4
#define CINc 64
#define COUTc 64
#define Hn   128
#define Wn   128
#define HW   (Hn * Wn)
#define KKc  9
#define NOFF 18

typedef short bf16x8 __attribute__((ext_vector_type(8)));
typedef float f32x4  __attribute__((ext_vector_type(4)));

__device__ inline unsigned short f2bf(float f) {   // RNE fp32 -> bf16
    unsigned int u = __float_as_uint(f);
    return (unsigned short)((u + 0x7fffu + ((u >> 16) & 1u)) >> 16);
}

// 16B global -> LDS DMA. lds base wave-uniform; HW writes lane's 16B at
// ldsbase + lane*16.
__device__ inline void dma16(const void* g, void* l) {
#if __has_builtin(__builtin_amdgcn_global_load_lds)
    __builtin_amdgcn_global_load_lds(
        (__attribute__((address_space(1))) void*)(g),
        (__attribute__((address_space(3))) void*)(l), 16, 0, 0);
#else
    *(uint4*)l = *(const uint4*)g;
#endif
}

// ---------------------------------------------------------------------------
// prep_all: blocks 0..1023 transpose x -> channel-last bf16 xt;
// blocks 1024..1239 build lane-order swizzled weight tables.
// ---------------------------------------------------------------------------
__global__ __launch_bounds__(256) void prep_all(
        const float* __restrict__ x, unsigned short* __restrict__ xt,
        const float* __restrict__ w_off, const float* __restrict__ w_def,
        unsigned short* __restrict__ wkb_sw, unsigned short* __restrict__ wob_sw) {
    int gb = blockIdx.x;
    int t  = threadIdx.x;
    if (gb < 1024) {
        __shared__ float s[64][65];
        int half = gb & 1;
        int h    = (gb >> 1) & 127;
        int b    = gb >> 8;
        int w0   = half * 64;
        int w = t & 63, cg = t >> 6;

        const float* xb = x + (size_t)b * CINc * HW + (size_t)h * Wn + w0 + w;
        #pragma unroll
        for (int i = 0; i < 16; ++i) {
            int c = cg * 16 + i;
            s[c][w] = xb[(size_t)c * HW];
        }
        __syncthreads();

        int cpair = t & 31, pxg = t >> 5;
        unsigned* xtp = (unsigned*)xt;
        #pragma unroll
        for (int i = 0; i < 8; ++i) {
            int px = pxg * 8 + i;
            float v0 = s[cpair * 2][px], v1 = s[cpair * 2 + 1][px];
            unsigned d = (unsigned)f2bf(v0) | ((unsigned)f2bf(v1) << 16);
            xtp[(((size_t)(b * Hn + h) * Wn) + w0 + px) * 32 + cpair] = d;
        }
        return;
    }
    int idx = (gb - 1024) * 256 + t;
    if (idx < 36864) {
        int j = idx & 7, l = (idx >> 3) & 63, s = idx >> 9;
        int k = s >> 3, kc = (s >> 2) & 1, ot = s & 3;
        int l15 = l & 15, quad = l >> 4;
        int o = ot * 16 + l15, c = kc * 32 + quad * 8 + j;
        wkb_sw[idx] = f2bf(w_def[((size_t)o * 64 + c) * 9 + k]);
    }
    int i2 = idx - 36864;
    if (i2 >= 0 && i2 < 18432) {
        int j = i2 & 7, l = (i2 >> 3) & 63, s = i2 >> 9;
        int tt = s >> 2, kc = (s >> 1) & 1, mt = s & 1;
        int l15 = l & 15, quad = l >> 4;
        int m = mt * 16 + l15, c = kc * 32 + quad * 8 + j;
        unsigned short v = 0;
        if (m < NOFF) v = f2bf(w_off[((size_t)m * 64 + c) * 9 + tt]);
        wob_sw[i2] = v;
    }
}

// ---------------------------------------------------------------------------
// Fused deformable conv v10. Block = (b,h) FULL 128-px row, 512 thr (8 waves,
// wave w owns px w*16..w*16+15). LDS = s_w only (73.7 KB, time-shared
// wob->wkb) -> 2 blocks/CU = 16 waves = 50% occupancy (was 80.9 KB / 18.7%).
// phase-1 redistribution now via __shfl (wave-local pixel ownership) instead
// of s_ad/s_wh LDS tables. Otherwise identical to v9's proven structure.
// ---------------------------------------------------------------------------
__global__ __launch_bounds__(512, 4) void fused_deform_v10(
        const unsigned short* __restrict__ xt,
        const unsigned short* __restrict__ wob_sw,
        const unsigned short* __restrict__ wkb_sw,
        const float* __restrict__ b_off, float* __restrict__ out) {
    __shared__ bf16x8 s_w[72 * 64];         // 73728 B (wob 36 segs, wkb 72)

    int gid  = blockIdx.x;                  // 512
    int xcd  = gid & 7;
    int j    = gid >> 3;                    // 0..63
    int hh   = j & 15;
    int b    = j >> 4;
    int h    = xcd * 16 + hh;
    int tid  = threadIdx.x;
    int lane = tid & 63;
    int wave = __builtin_amdgcn_readfirstlane(tid >> 6);   // 0..7
    int l15  = lane & 15;
    int quad = lane >> 4;
    int p    = wave * 16 + l15;             // this lane's pixel col (0..127)

    // ---- stage wob -> s_w[0..36 segs) via DMA ----
    #pragma unroll
    for (int i = 0; i < 5; ++i) {
        int seg = i * 8 + wave;             // wave-uniform
        if (seg < 36) {
            int ebase = seg * 64;
            dma16((const uint4*)wob_sw + ebase + lane,
                  (char*)s_w + (size_t)ebase * 16);
        }
    }

    // ---- prefetch the 18 offset-tap fragments ----
    uint4 L[9][2];
    unsigned msk[9];
    const unsigned short* xtb = xt + (size_t)b * HW * 64;
    #pragma unroll
    for (int t9 = 0; t9 < 9; ++t9) {
        int ty = t9 / 3, tx = t9 % 3;
        int y  = h - 1 + ty;
        int xg = p - 1 + tx;
        bool v = (y >= 0) && (y < Hn) && (xg >= 0) && (xg < Wn);
        msk[t9] = v ? 0xFFFFFFFFu : 0u;
        int yc = min(max(y, 0), Hn - 1);
        int xc = min(max(xg, 0), Wn - 1);
        size_t base = ((size_t)yc * Wn + xc) * 64;
        L[t9][0] = *(const uint4*)(xtb + base + quad * 8);
        L[t9][1] = *(const uint4*)(xtb + base + 32 + quad * 8);
    }
    __syncthreads();                        // bar0: wob DMA + prefetch drained

    // ---- offset conv phase: 36 MFMA ----
    f32x4 oa0 = (f32x4){0.f, 0.f, 0.f, 0.f};
    f32x4 oa1 = (f32x4){0.f, 0.f, 0.f, 0.f};
    #pragma unroll
    for (int t9 = 0; t9 < 9; ++t9) {
        unsigned m = msk[t9];
        #pragma unroll
        for (int kc = 0; kc < 2; ++kc) {
            union { bf16x8 v; uint4 u; } bf;
            bf.u = L[t9][kc];
            bf.u.x &= m; bf.u.y &= m; bf.u.z &= m; bf.u.w &= m;
            bf16x8 a0 = s_w[((t9 * 2 + kc) * 2 + 0) * 64 + lane];
            bf16x8 a1 = s_w[((t9 * 2 + kc) * 2 + 1) * 64 + lane];
            oa0 = __builtin_amdgcn_mfma_f32_16x16x32_bf16(a0, bf.v, oa0, 0, 0, 0);
            oa1 = __builtin_amdgcn_mfma_f32_16x16x32_bf16(a1, bf.v, oa1, 0, 0, 0);
        }
    }

    // ---- phase-1 in registers; lane (l15,q) computes taps 2q,2q+1 (+8:q0)
    unsigned my_ad[3]  = {0, 0, 0};
    unsigned my_w01[3] = {0, 0, 0};
    unsigned my_w23[3] = {0, 0, 0};
    auto phase1 = [&](int k, float dy, float dx, int slot) {
        float py  = (float)(h - 1 + k / 3) + dy;
        float pxf = (float)(p - 1 + k % 3) + dx;
        float y0f = floorf(py), x0f = floorf(pxf);
        float fy = py - y0f, fx = pxf - x0f;
        int y0 = (int)y0f, x0 = (int)x0f;
        bool vy0 = (y0 >= 0) & (y0 < Hn);
        bool vy1 = (y0 + 1 >= 0) & (y0 + 1 < Hn);
        bool vx0 = (x0 >= 0) & (x0 < Wn);
        bool vx1 = (x0 + 1 >= 0) & (x0 + 1 < Wn);
        float wy0 = vy0 ? 1.f - fy : 0.f;
        float wy1 = vy1 ? fy : 0.f;
        float wx0 = vx0 ? 1.f - fx : 0.f;
        float wx1 = vx1 ? fx : 0.f;
        int xc = min(max(x0, 0), Wn - 2);               // pair base
        bool sel0 = (min(max(x0, 0), Wn - 1) != xc);
        bool sel1 = ((min(max(x0 + 1, 0), Wn - 1) - xc) == 1);
        float Wa = (sel0 ? 0.f : wx0) + (sel1 ? 0.f : wx1);
        float Wb = (sel0 ? wx0 : 0.f) + (sel1 ? wx1 : 0.f);
        int yc0 = min(max(y0, 0), Hn - 1), yc1 = min(max(y0 + 1, 0), Hn - 1);
        union { __half2 hv; unsigned u; } c01, c23;
        c01.hv = __floats2half2_rn(wy0 * Wa, wy0 * Wb);
        c23.hv = __floats2half2_rn(wy1 * Wa, wy1 * Wb);
        my_ad[slot]  = (unsigned)yc0 | ((unsigned)yc1 << 8) | ((unsigned)xc << 16);
        my_w01[slot] = c01.u;
        my_w23[slot] = c23.u;
    };
    int kb = quad * 2;
    phase1(kb,     oa0[0] + b_off[4 * quad],     oa0[1] + b_off[4 * quad + 1], 0);
    phase1(kb + 1, oa0[2] + b_off[4 * quad + 2], oa0[3] + b_off[4 * quad + 3], 1);
    if (quad == 0)
        phase1(8, oa1[0] + b_off[16], oa1[1] + b_off[17], 2);
    __syncthreads();                        // bar1: all wob ds_reads done

    // ---- overwrite s_w with wkb via DMA (issue first, shuffles cover) ----
    #pragma unroll
    for (int i = 0; i < 9; ++i) {
        int seg = i * 8 + wave;             // 72 segs over 8 waves
        int ebase = seg * 64;
        dma16((const uint4*)wkb_sw + ebase + lane,
              (char*)s_w + (size_t)ebase * 16);
    }

    // ---- redistribute phase-1 via shuffles (wave-local, no LDS) ----
    unsigned at[KKc], ab[KKc];
    float Wf[KKc][4];
    #pragma unroll
    for (int k = 0; k < KKc; ++k) {
        int src  = (k < 8) ? ((k >> 1) * 16 + l15) : l15;
        int slot = (k < 8) ? (k & 1) : 2;
        unsigned ad  = (unsigned)__shfl((int)my_ad[slot],  src, 64);
        unsigned w01 = (unsigned)__shfl((int)my_w01[slot], src, 64);
        unsigned w23 = (unsigned)__shfl((int)my_w23[slot], src, 64);
        int xc = (int)(ad >> 16);
        at[k] = (unsigned)(((ad & 255u) * Wn + xc) * 64);
        ab[k] = (unsigned)((((ad >> 8) & 255u) * Wn + xc) * 64);
        union { unsigned u; __half2 hv; } c01, c23;
        c01.u = w01; c23.u = w23;
        Wf[k][0] = __low2float(c01.hv); Wf[k][1] = __high2float(c01.hv);
        Wf[k][2] = __low2float(c23.hv); Wf[k][3] = __high2float(c23.hv);
    }
    __syncthreads();                        // bar2: wkb visible

    f32x4 acc[4];
    #pragma unroll
    for (int ot = 0; ot < 4; ++ot) acc[ot] = (f32x4){0.f, 0.f, 0.f, 0.f};

    // ---- software-pipelined barrier-free main loop ----
    uint4 R[2][8];
    int co0 = quad * 8, co1 = 32 + quad * 8;

    #define FETCH(kk, st)                                            \
        do {                                                         \
            R[st][0] = *(const uint4*)(xtb + at[kk] + co0);          \
            R[st][1] = *(const uint4*)(xtb + at[kk] + 64 + co0);     \
            R[st][2] = *(const uint4*)(xtb + ab[kk] + co0);          \
            R[st][3] = *(const uint4*)(xtb + ab[kk] + 64 + co0);     \
            R[st][4] = *(const uint4*)(xtb + at[kk] + co1);          \
            R[st][5] = *(const uint4*)(xtb + at[kk] + 64 + co1);     \
            R[st][6] = *(const uint4*)(xtb + ab[kk] + co1);          \
            R[st][7] = *(const uint4*)(xtb + ab[kk] + 64 + co1);     \
        } while (0)

    FETCH(0, 0);
    #pragma unroll
    for (int k = 0; k < KKc; ++k) {
        if (k < KKc - 1) FETCH(k + 1, (k + 1) & 1);
        const uint4* C = R[k & 1];
        float W0 = Wf[k][0], W1 = Wf[k][1], W2 = Wf[k][2], W3 = Wf[k][3];
        #pragma unroll
        for (int kc = 0; kc < 2; ++kc) {
            const unsigned* t0 = (const unsigned*)&C[kc * 4 + 0];
            const unsigned* t1 = (const unsigned*)&C[kc * 4 + 1];
            const unsigned* b0 = (const unsigned*)&C[kc * 4 + 2];
            const unsigned* b1 = (const unsigned*)&C[kc * 4 + 3];
            union { bf16x8 v; unsigned u[4]; } bf;
            #pragma unroll
            for (int jd = 0; jd < 4; ++jd) {
                float t0l = __uint_as_float(t0[jd] << 16);
                float t0h = __uint_as_float(t0[jd] & 0xFFFF0000u);
                float t1l = __uint_as_float(t1[jd] << 16);
                float t1h = __uint_as_float(t1[jd] & 0xFFFF0000u);
                float b0l = __uint_as_float(b0[jd] << 16);
                float b0h = __uint_as_float(b0[jd] & 0xFFFF0000u);
                float b1l = __uint_as_float(b1[jd] << 16);
                float b1h = __uint_as_float(b1[jd] & 0xFFFF0000u);
                float vl = W0 * t0l + W1 * t1l + W2 * b0l + W3 * b1l;
                float vh = W0 * t0h + W1 * t1h + W2 * b0h + W3 * b1h;
                bf.u[jd] = (unsigned)f2bf(vl) | ((unsigned)f2bf(vh) << 16);
            }
            #pragma unroll
            for (int ot = 0; ot < 4; ++ot) {
                bf16x8 af = s_w[((k * 2 + kc) * 4 + ot) * 64 + lane];
                acc[ot] = __builtin_amdgcn_mfma_f32_16x16x32_bf16(af, bf.v, acc[ot], 0, 0, 0);
            }
        }
    }
    #undef FETCH

    #pragma unroll
    for (int ot = 0; ot < 4; ++ot)
        #pragma unroll
        for (int r = 0; r < 4; ++r) {
            int o = ot * 16 + quad * 4 + r;
            out[(((size_t)b * COUTc + o) * Hn + h) * Wn + p] = acc[ot][r];
        }
}

// ---------------------------------------------------------------------------
extern "C" void kernel_launch(void* const* d_in, const int* in_sizes, int n_in,
                              void* d_out, int out_size, void* d_ws, size_t ws_size,
                              hipStream_t stream) {
    const float* x     = (const float*)d_in[0];
    const float* w_off = (const float*)d_in[1];
    const float* b_off = (const float*)d_in[2];
    const float* w_def = (const float*)d_in[3];
    float* out = (float*)d_out;

    char* ws = (char*)d_ws;
    unsigned short* xt = (unsigned short*)ws;                 // 8.39 MB
    ws += (size_t)Bn * HW * CINc * sizeof(unsigned short);
    unsigned short* wkb_sw = (unsigned short*)ws;             // 73728 B
    ws += 36864 * sizeof(unsigned short);
    unsigned short* wob_sw = (unsigned short*)ws;             // 36864 B

    prep_all<<<1024 + 216, 256, 0, stream>>>(x, xt, w_off, w_def, wkb_sw, wob_sw);
    fused_deform_v10<<<Bn * Hn, 512, 0, stream>>>(xt, wob_sw, wkb_sw, b_off, out);
}